// Round 8
// baseline (177.725 us; speedup 1.0000x reference)
//
#include <hip/hip_runtime.h>
#include <hip/hip_bf16.h>

#define N_NODES 50000
#define IN_C    96
#define HID_C   128
#define OUT_C   64
#define MROWS   50048 // 64-row-tile padded M

// Single-pass CSR build (R4-proven): each WG reserves per-bucket space via
// global atomicAdd on gcnt[NB]; partb re-ranks within buckets.
#define NB      200   // coarse buckets
#define BSZ     250   // nodes per bucket (200*250 = 50000)
#define WCHUNK  4096  // edges per workgroup (R4-proven occupancy point)
#define NWG     196   // ceil(800000/4096)
#define BCAP    8192  // per-bucket capacity (mean 4000, +66 sigma: safe)

// conv fusion split
#define XBLKS   2344  // ceil(50000*12/256)
#define WBLKS   160   // (128*192 + 128*128)/256

typedef __attribute__((ext_vector_type(8))) short short8;  // 8 bf16 (4 VGPR)
typedef __attribute__((ext_vector_type(4))) float f32x4;

// round-to-nearest-even fp32 -> bf16 bits
__device__ inline unsigned int f2bf(float f) {
    unsigned int u = __float_as_uint(f);
    return (u + 0x7fffu + ((u >> 16) & 1u)) >> 16;
}
__device__ inline unsigned int pack2(float lo, float hi) {
    return f2bf(lo) | (f2bf(hi) << 16);
}
__device__ inline float blo(unsigned int u) { return __uint_as_float(u << 16); }
__device__ inline float bhi(unsigned int u) { return __uint_as_float(u & 0xffff0000u); }

// ---------------------------------------------------------------------------
// Fused converter (runs FIRST): blocks [0,XBLKS) convert x fp32 -> xb bf16;
// blocks [XBLKS,..) build W1t[128][192] / W2t[128][128]. Last block also
// zeroes gcnt (stream order guarantees it lands before csr_scatter).
// ---------------------------------------------------------------------------
__global__ __launch_bounds__(256) void conv_all_kernel(
    const float* __restrict__ x, uint4* __restrict__ xb4,
    const float* __restrict__ w1l, const float* __restrict__ w1r,
    const float* __restrict__ w2l, const float* __restrict__ w2r,
    unsigned short* __restrict__ wt1, unsigned short* __restrict__ wt2,
    int* __restrict__ gcnt)
{
    int blk = blockIdx.x;
    if (blk == gridDim.x - 1 && threadIdx.x < NB) gcnt[threadIdx.x] = 0;
    if (blk < XBLKS) {
        int idx = blk * 256 + threadIdx.x;
        if (idx >= N_NODES * 12) return;
        const float4* x4 = (const float4*)x;
        float4 u = x4[(size_t)idx * 2];
        float4 v = x4[(size_t)idx * 2 + 1];
        uint4 w;
        w.x = pack2(u.x, u.y); w.y = pack2(u.z, u.w);
        w.z = pack2(v.x, v.y); w.w = pack2(v.z, v.w);
        xb4[idx] = w;
    } else {
        int i = (blk - XBLKS) * 256 + threadIdx.x;
        if (i < 128 * 192) {
            int col = i / 192, k = i - col * 192;
            float v = (k < 96) ? w1l[k * 128 + col] : w1r[(k - 96) * 128 + col];
            wt1[i] = (unsigned short)f2bf(v);
        } else {
            int j = i - 128 * 192;
            int col = j / 128, k = j - col * 128;
            float v = (col < 64) ? w2l[k * 64 + col] : w2r[k * 64 + col - 64];
            wt2[j] = (unsigned short)f2bf(v);
        }
    }
}

// ---------------------------------------------------------------------------
// CSR pass 1 (single-pass scatter): stage chunk in LDS (int4 loads), LDS
// 200-bin histogram, reserve space per bucket via global atomicAdd, then
// rank+scatter packed edges (localdst<<17 | src) into bucket regions.
// ---------------------------------------------------------------------------
__global__ __launch_bounds__(256) void csr_scatter(
    const int* __restrict__ src, const int* __restrict__ dst,
    int* __restrict__ gcnt, unsigned int* __restrict__ pairs, int E)
{
    __shared__ int lsrc[WCHUNK];
    __shared__ int ldst[WCHUNK];
    __shared__ int h[NB];      // hist, then reused as cur
    __shared__ int wbase[NB];  // this WG's reserved base per bucket
    int t = threadIdx.x;
    int base_e = blockIdx.x * WCHUNK;
    int rem = E - base_e; if (rem > WCHUNK) rem = WCHUNK;
    {
        const int4* s4 = (const int4*)(src + base_e);
        const int4* d4 = (const int4*)(dst + base_e);
        int nv = rem >> 2;
        for (int k = t; k < nv; k += 256) {
            ((int4*)lsrc)[k] = s4[k];
            ((int4*)ldst)[k] = d4[k];
        }
        for (int i = (nv << 2) + t; i < rem; i += 256) {
            lsrc[i] = src[base_e + i];
            ldst[i] = dst[base_e + i];
        }
    }
    if (t < NB) h[t] = 0;
    __syncthreads();
    for (int i = t; i < rem; i += 256)
        atomicAdd(&h[ldst[i] / BSZ], 1);
    __syncthreads();
    if (t < NB) {
        wbase[t] = atomicAdd(&gcnt[t], h[t]);
        h[t] = 0;                                  // becomes cur
    }
    __syncthreads();
    for (int i = t; i < rem; i += 256) {
        int d = ldst[i];
        int b = d / BSZ;
        int r = atomicAdd(&h[b], 1);
        pairs[b * BCAP + wbase[b] + r] =
            ((unsigned)(d - b * BSZ) << 17) | (unsigned)lsrc[i];
    }
}

// ---------------------------------------------------------------------------
// CSR pass 2: per-bucket fine CSR (bucket b region = [b*BCAP, b*BCAP+gcnt[b])).
// LDS 250-bin histogram + scan + rank; uint4-vectorized 4-wide loops.
// ---------------------------------------------------------------------------
__global__ __launch_bounds__(256) void partb_csr(
    const unsigned int* __restrict__ pairs, const int* __restrict__ gcnt,
    int* __restrict__ rowstart, int* __restrict__ cnt,
    int* __restrict__ adj)
{
    __shared__ int h[256];
    __shared__ int buf[256];
    __shared__ int cur[256];
    int b = blockIdx.x;
    int t = threadIdx.x;
    int beg = b * BCAP;
    int n = gcnt[b];
    int node0 = b * BSZ;
    h[t] = 0;
    __syncthreads();
    const uint4* p4 = (const uint4*)(pairs + beg);
    int nv = n >> 2;
    for (int k = t; k < nv; k += 256) {
        uint4 u = p4[k];
        atomicAdd(&h[u.x >> 17], 1);
        atomicAdd(&h[u.y >> 17], 1);
        atomicAdd(&h[u.z >> 17], 1);
        atomicAdd(&h[u.w >> 17], 1);
    }
    for (int i = (nv << 2) + t; i < n; i += 256)
        atomicAdd(&h[pairs[beg + i] >> 17], 1);
    __syncthreads();
    int c = h[t];
    buf[t] = c;
    __syncthreads();
    for (int off = 1; off < 256; off <<= 1) {       // inclusive scan
        int v = (t >= off) ? buf[t - off] : 0;
        __syncthreads();
        buf[t] += v;
        __syncthreads();
    }
    int excl = buf[t] - c;
    if (t < BSZ) {
        rowstart[node0 + t] = beg + excl;
        cnt[node0 + t] = c;
    }
    cur[t] = beg + excl;
    __syncthreads();
    for (int k = t; k < nv; k += 256) {
        uint4 u = p4[k];
        int p0 = atomicAdd(&cur[u.x >> 17], 1);
        int p1 = atomicAdd(&cur[u.y >> 17], 1);
        int p2 = atomicAdd(&cur[u.z >> 17], 1);
        int p3 = atomicAdd(&cur[u.w >> 17], 1);
        adj[p0] = (int)(u.x & 0x1FFFFu);
        adj[p1] = (int)(u.y & 0x1FFFFu);
        adj[p2] = (int)(u.z & 0x1FFFFu);
        adj[p3] = (int)(u.w & 0x1FFFFu);
    }
    for (int i = (nv << 2) + t; i < n; i += 256) {
        unsigned int u = pairs[beg + i];
        int pos = atomicAdd(&cur[u >> 17], 1);
        adj[pos] = (int)(u & 0x1FFFFu);
    }
}

// ---------------------------------------------------------------------------
// Fused gather1 + GEMM1 + GEMM2 (bf16 MFMA), 64-row tiles. R8: each block
// gathers its own 64 nodes' neighbor means DIRECTLY into the A-tile LDS
// (left 12 chunks) -- no global agg array, no separate gather1 kernel.
// Co-resident blocks pipeline: one block's latency-bound gather overlaps
// another's MFMA. Weights stay global->register (R7-proven).
//   h = relu([agg|x] @ W1t^T + b1) in LDS; [p|q] = h @ W2t^T.
// ---------------------------------------------------------------------------
__global__ __launch_bounds__(256) void gemm12_gather(
    const int* __restrict__ rowstart, const int* __restrict__ cnt,
    const int* __restrict__ adj, const uint4* __restrict__ xb4,
    const uint4* __restrict__ w1t4, const uint4* __restrict__ w2t4,
    const float* __restrict__ b1, const float* __restrict__ b2,
    unsigned short* __restrict__ p, float* __restrict__ out)
{
    constexpr int KP = 200;   // stage-1 A stride in shorts (192+8 pad)
    constexpr int KQ = 136;   // stage-2 A stride in shorts (128+8 pad)
    __shared__ unsigned short la[64 * KP];    // 25600 B (reused for h-tile)
    int t = threadIdx.x;
    uint4* la4 = (uint4*)la;
    int row0 = blockIdx.x * 64;

    // stage xb right half first (streaming loads go in flight under gather)
    for (int i = t; i < 64 * 12; i += 256) {
        int r = i / 12, c = i - r * 12;
        // rows >= N_NODES read xb pad rows (valid mem, rows discarded)
        la4[r * 25 + 12 + c] = xb4[(size_t)(row0 + r) * 12 + c];
    }

    // gather left half: unit = (local row, chunk); mean of neighbors' xb
    for (int u = t; u < 64 * 12; u += 256) {
        int r = u / 12, c = u - r * 12;
        int node = row0 + r;
        if (node >= N_NODES) continue;   // LDS garbage OK: MFMA rows indep.
        int beg = rowstart[node];
        int d = cnt[node];
        int end = beg + d;
        float a0=0,a1=0,a2=0,a3=0,a4=0,a5=0,a6=0,a7=0;
        float b0=0,b1_=0,b2_=0,b3=0,b4=0,b5=0,b6=0,b7=0;
        int j = beg;
        for (; j + 3 < end; j += 4) {
            int s0 = adj[j];
            int s1 = adj[j + 1];
            int s2 = adj[j + 2];
            int s3 = adj[j + 3];
            uint4 uu = xb4[(size_t)s0 * 12 + c];
            uint4 vv = xb4[(size_t)s1 * 12 + c];
            uint4 ww = xb4[(size_t)s2 * 12 + c];
            uint4 zz = xb4[(size_t)s3 * 12 + c];
            a0 += blo(uu.x); a1 += bhi(uu.x); a2 += blo(uu.y); a3 += bhi(uu.y);
            a4 += blo(uu.z); a5 += bhi(uu.z); a6 += blo(uu.w); a7 += bhi(uu.w);
            b0 += blo(vv.x); b1_ += bhi(vv.x); b2_ += blo(vv.y); b3 += bhi(vv.y);
            b4 += blo(vv.z); b5 += bhi(vv.z); b6 += blo(vv.w); b7 += bhi(vv.w);
            a0 += blo(ww.x); a1 += bhi(ww.x); a2 += blo(ww.y); a3 += bhi(ww.y);
            a4 += blo(ww.z); a5 += bhi(ww.z); a6 += blo(ww.w); a7 += bhi(ww.w);
            b0 += blo(zz.x); b1_ += bhi(zz.x); b2_ += blo(zz.y); b3 += bhi(zz.y);
            b4 += blo(zz.z); b5 += bhi(zz.z); b6 += blo(zz.w); b7 += bhi(zz.w);
        }
        for (; j < end; j++) {
            uint4 uu = xb4[(size_t)adj[j] * 12 + c];
            a0 += blo(uu.x); a1 += bhi(uu.x); a2 += blo(uu.y); a3 += bhi(uu.y);
            a4 += blo(uu.z); a5 += bhi(uu.z); a6 += blo(uu.w); a7 += bhi(uu.w);
        }
        a0 += b0; a1 += b1_; a2 += b2_; a3 += b3;
        a4 += b4; a5 += b5; a6 += b6; a7 += b7;
        float id = 1.0f / (float)max(d, 1);
        uint4 w;
        w.x = pack2(a0 * id, a1 * id); w.y = pack2(a2 * id, a3 * id);
        w.z = pack2(a4 * id, a5 * id); w.w = pack2(a6 * id, a7 * id);
        la4[r * 25 + c] = w;
    }

    int wave = t >> 6, lane = t & 63;
    int m = lane & 15, half = lane >> 4;          // half: 0..3
    int koff = half * 8;

    // B1 fragments from global (L2-hot; short live range -> low VGPR hold).
    // W1t is [128][192] bf16 = [128][24] short8; frag = col*24 + kk*4 + half.
    const short8* w1s = (const short8*)w1t4;
    short8 B1r[6][2];
#pragma unroll
    for (int kk = 0; kk < 6; kk++) {
        B1r[kk][0] = w1s[(wave * 32 + m)      * 24 + kk * 4 + half];
        B1r[kk][1] = w1s[(wave * 32 + 16 + m) * 24 + kk * 4 + half];
    }
    __syncthreads();

    f32x4 acc[4][2] = {};
#pragma unroll
    for (int kk = 0; kk < 6; kk++) {
        int k0 = kk * 32;
#pragma unroll
        for (int g = 0; g < 4; g++) {
            short8 A = *(const short8*)&la[(g * 16 + m) * KP + k0 + koff];
            acc[g][0] = __builtin_amdgcn_mfma_f32_16x16x32_bf16(A, B1r[kk][0], acc[g][0], 0, 0, 0);
            acc[g][1] = __builtin_amdgcn_mfma_f32_16x16x32_bf16(A, B1r[kk][1], acc[g][1], 0, 0, 0);
        }
    }
    __syncthreads();   // all waves done reading la before h overwrite

    // B2 fragments from global (issued before h-write to hide L2 latency).
    const short8* w2s = (const short8*)w2t4;
    short8 B2r[4][2];
#pragma unroll
    for (int kk = 0; kk < 4; kk++) {
        B2r[kk][0] = w2s[(wave * 32 + m)      * 16 + kk * 4 + half];
        B2r[kk][1] = w2s[(wave * 32 + 16 + m) * 16 + kk * 4 + half];
    }

    // h-tile (bias+relu, bf16) -> la with stride KQ
    int col0 = wave * 32 + m, col1 = col0 + 16;
    {
        float bias0 = b1[col0], bias1 = b1[col1];
#pragma unroll
        for (int g = 0; g < 4; g++) {
#pragma unroll
            for (int reg = 0; reg < 4; reg++) {
                int hr = g * 16 + half * 4 + reg;
                la[hr * KQ + col0] = (unsigned short)f2bf(fmaxf(acc[g][0][reg] + bias0, 0.f));
                la[hr * KQ + col1] = (unsigned short)f2bf(fmaxf(acc[g][1][reg] + bias1, 0.f));
            }
        }
    }
    __syncthreads();

    f32x4 acc2[4][2] = {};
#pragma unroll
    for (int kk = 0; kk < 4; kk++) {
        int k0 = kk * 32;
#pragma unroll
        for (int g = 0; g < 4; g++) {
            short8 A = *(const short8*)&la[(g * 16 + m) * KQ + k0 + koff];
            acc2[g][0] = __builtin_amdgcn_mfma_f32_16x16x32_bf16(A, B2r[kk][0], acc2[g][0], 0, 0, 0);
            acc2[g][1] = __builtin_amdgcn_mfma_f32_16x16x32_bf16(A, B2r[kk][1], acc2[g][1], 0, 0, 0);
        }
    }
#pragma unroll
    for (int g = 0; g < 4; g++) {
#pragma unroll
        for (int reg = 0; reg < 4; reg++) {
            int r = row0 + g * 16 + half * 4 + reg;
            if (r >= N_NODES) continue;
            float v0 = acc2[g][0][reg], v1 = acc2[g][1][reg];
            if (col0 < 64) p[(size_t)r * 64 + col0] = (unsigned short)f2bf(v0);
            else           out[(size_t)r * 64 + col0 - 64] = v0 + b2[col0 - 64];
            if (col1 < 64) p[(size_t)r * 64 + col1] = (unsigned short)f2bf(v1);
            else           out[(size_t)r * 64 + col1 - 64] = v1 + b2[col1 - 64];
        }
    }
}

// ---------------------------------------------------------------------------
// Gather 2 + finalize: out[n] += (sum_{j in N(n)} p[j]) / deg(n)
// thread = (node, 16B chunk c in 0..7); 4-edge unroll (R4-proven).
// ---------------------------------------------------------------------------
__global__ __launch_bounds__(256) void gather2_kernel(
    const int* __restrict__ rowstart, const int* __restrict__ cnt,
    const int* __restrict__ adj, const uint4* __restrict__ p4,
    float* __restrict__ out)
{
    int idx = blockIdx.x * 256 + threadIdx.x;
    if (idx >= N_NODES * 8) return;
    int node = idx >> 3;
    int c = idx & 7;
    int beg = rowstart[node];
    int d = cnt[node];
    int end = beg + d;
    float a0=0,a1=0,a2=0,a3=0,a4=0,a5=0,a6=0,a7=0;
    float b0=0,b1=0,b2=0,b3=0,b4=0,b5=0,b6=0,b7=0;
    int j = beg;
    for (; j + 3 < end; j += 4) {
        int s0 = adj[j];
        int s1 = adj[j + 1];
        int s2 = adj[j + 2];
        int s3 = adj[j + 3];
        uint4 u = p4[(size_t)s0 * 8 + c];
        uint4 v = p4[(size_t)s1 * 8 + c];
        uint4 w = p4[(size_t)s2 * 8 + c];
        uint4 z = p4[(size_t)s3 * 8 + c];
        a0 += blo(u.x); a1 += bhi(u.x); a2 += blo(u.y); a3 += bhi(u.y);
        a4 += blo(u.z); a5 += bhi(u.z); a6 += blo(u.w); a7 += bhi(u.w);
        b0 += blo(v.x); b1 += bhi(v.x); b2 += blo(v.y); b3 += bhi(v.y);
        b4 += blo(v.z); b5 += bhi(v.z); b6 += blo(v.w); b7 += bhi(v.w);
        a0 += blo(w.x); a1 += bhi(w.x); a2 += blo(w.y); a3 += bhi(w.y);
        a4 += blo(w.z); a5 += bhi(w.z); a6 += blo(w.w); a7 += bhi(w.w);
        b0 += blo(z.x); b1 += bhi(z.x); b2 += blo(z.y); b3 += bhi(z.y);
        b4 += blo(z.z); b5 += bhi(z.z); b6 += blo(z.w); b7 += bhi(z.w);
    }
    for (; j < end; j++) {
        int s0 = adj[j];
        uint4 u = p4[(size_t)s0 * 8 + c];
        a0 += blo(u.x); a1 += bhi(u.x); a2 += blo(u.y); a3 += bhi(u.y);
        a4 += blo(u.z); a5 += bhi(u.z); a6 += blo(u.w); a7 += bhi(u.w);
    }
    a0 += b0; a1 += b1; a2 += b2; a3 += b3;
    a4 += b4; a5 += b5; a6 += b6; a7 += b7;
    float id = 1.0f / (float)max(d, 1);
    float4* o4 = (float4*)out;
    size_t base = (size_t)node * 16 + 2 * c;
    float4 u = o4[base], v = o4[base + 1];
    u.x = fmaf(a0, id, u.x); u.y = fmaf(a1, id, u.y);
    u.z = fmaf(a2, id, u.z); u.w = fmaf(a3, id, u.w);
    v.x = fmaf(a4, id, v.x); v.y = fmaf(a5, id, v.y);
    v.z = fmaf(a6, id, v.z); v.w = fmaf(a7, id, v.w);
    o4[base] = u; o4[base + 1] = v;
}

extern "C" void kernel_launch(void* const* d_in, const int* in_sizes, int n_in,
                              void* d_out, int out_size, void* d_ws, size_t ws_size,
                              hipStream_t stream)
{
    const float* x   = (const float*)d_in[0];
    const int*   ei  = (const int*)d_in[1];
    const float* w1l = (const float*)d_in[2];
    const float* w1r = (const float*)d_in[3];
    const float* b1  = (const float*)d_in[4];
    const float* w2l = (const float*)d_in[5];
    const float* w2r = (const float*)d_in[6];
    const float* b2  = (const float*)d_in[7];
    float* out = (float*)d_out;

    int E = in_sizes[1] / 2;                  // edge_index is [2, E]
    const int* src = ei;
    const int* dst = ei + E;

    // Workspace layout (4B units, arrays kept 16B-aligned).
    int* gcnt     = (int*)d_ws;                        // 256 (200 used)
    int* cnt      = gcnt + 256;                        // 50000
    int* rowstart = cnt + N_NODES;                     // 50000
    unsigned int* pairs = (unsigned int*)(rowstart + N_NODES); // NB*BCAP
    int* adj      = (int*)(pairs + NB * BCAP);         // NB*BCAP
    unsigned short* xb  = (unsigned short*)(adj + NB * BCAP); // MROWS*96 bf16
    unsigned short* p   = xb + (size_t)MROWS * IN_C;   // 50000*64 bf16
    unsigned short* Wt1 = p  + (size_t)N_NODES * 64;   // 128*192 bf16
    unsigned short* Wt2 = Wt1 + 128 * 192;             // 128*128 bf16

    // conv first (also zeroes gcnt; stream order covers the dependency)
    conv_all_kernel<<<XBLKS + WBLKS, 256, 0, stream>>>(
        x, (uint4*)xb, w1l, w1r, w2l, w2r, Wt1, Wt2, gcnt);

    // CSR build: 2 kernels (single-pass bucket scatter + per-bucket CSR)
    csr_scatter<<<NWG, 256, 0, stream>>>(src, dst, gcnt, pairs, E);
    partb_csr<<<NB, 256, 0, stream>>>(pairs, gcnt, rowstart, cnt, adj);

    // fused gather1 + GEMM1 + GEMM2
    gemm12_gather<<<MROWS / 64, 256, 0, stream>>>(
        rowstart, cnt, adj, (const uint4*)xb,
        (const uint4*)Wt1, (const uint4*)Wt2, b1, b2, p, out);

    gather2_kernel<<<(N_NODES * 8 + 255) / 256, 256, 0, stream>>>(
        rowstart, cnt, adj, (const uint4*)p, out);
}

// Round 9
// 161.247 us; speedup vs baseline: 1.1022x; 1.1022x over previous
//
#include <hip/hip_runtime.h>
#include <hip/hip_bf16.h>

#define N_NODES 50000
#define IN_C    96
#define HID_C   128
#define OUT_C   64
#define MROWS   50048 // 64-row-tile padded M

// Single-pass CSR build (R4/R7-proven params): each WG reserves per-bucket
// space via global atomicAdd on gcnt[NB]; partb re-ranks within buckets.
#define NB      200   // coarse buckets
#define BSZ     250   // nodes per bucket (200*250 = 50000)
#define WCHUNK  4096  // edges per workgroup (R4-proven occupancy point)
#define NWG     196   // ceil(800000/4096)
#define BCAP    8192  // per-bucket capacity (mean 4000, +66 sigma: safe)

// conv fusion split (conv blocks appended after scatter blocks)
#define XBLKS   2344  // ceil(50000*12/256)
#define WBLKS   160   // (128*192 + 128*128)/256

typedef __attribute__((ext_vector_type(8))) short short8;  // 8 bf16 (4 VGPR)
typedef __attribute__((ext_vector_type(4))) float f32x4;

// round-to-nearest-even fp32 -> bf16 bits
__device__ inline unsigned int f2bf(float f) {
    unsigned int u = __float_as_uint(f);
    return (u + 0x7fffu + ((u >> 16) & 1u)) >> 16;
}
__device__ inline unsigned int pack2(float lo, float hi) {
    return f2bf(lo) | (f2bf(hi) << 16);
}
__device__ inline float blo(unsigned int u) { return __uint_as_float(u << 16); }
__device__ inline float bhi(unsigned int u) { return __uint_as_float(u & 0xffff0000u); }

// ---------------------------------------------------------------------------
// Fused scatter+conv (R9): blocks [0,NWG) = single-pass bucket scatter
// (latency-bound, <10% busy); blocks [NWG,NWG+XBLKS) stream x fp32->bf16;
// rest build W1t[128][192]/W2t[128][128]. The streaming conv work executes
// under the scatter's latency stalls -- one launch boundary removed vs R7.
// gcnt is zeroed by a preceding hipMemsetAsync on the same stream.
// ---------------------------------------------------------------------------
__global__ __launch_bounds__(256) void scatter_conv_kernel(
    const int* __restrict__ src, const int* __restrict__ dst,
    int* __restrict__ gcnt, unsigned int* __restrict__ pairs, int E,
    const float* __restrict__ x, uint4* __restrict__ xb4,
    const float* __restrict__ w1l, const float* __restrict__ w1r,
    const float* __restrict__ w2l, const float* __restrict__ w2r,
    unsigned short* __restrict__ wt1, unsigned short* __restrict__ wt2)
{
    __shared__ int lsrc[WCHUNK];
    __shared__ int ldst[WCHUNK];
    __shared__ int h[NB];      // hist, then reused as cur
    __shared__ int wbase[NB];  // this WG's reserved base per bucket
    int blk = blockIdx.x;
    int t = threadIdx.x;
    if (blk < NWG) {
        int base_e = blk * WCHUNK;
        int rem = E - base_e; if (rem > WCHUNK) rem = WCHUNK;
        {
            const int4* s4 = (const int4*)(src + base_e);
            const int4* d4 = (const int4*)(dst + base_e);
            int nv = rem >> 2;
            for (int k = t; k < nv; k += 256) {
                ((int4*)lsrc)[k] = s4[k];
                ((int4*)ldst)[k] = d4[k];
            }
            for (int i = (nv << 2) + t; i < rem; i += 256) {
                lsrc[i] = src[base_e + i];
                ldst[i] = dst[base_e + i];
            }
        }
        if (t < NB) h[t] = 0;
        __syncthreads();
        for (int i = t; i < rem; i += 256)
            atomicAdd(&h[ldst[i] / BSZ], 1);
        __syncthreads();
        if (t < NB) {
            wbase[t] = atomicAdd(&gcnt[t], h[t]);
            h[t] = 0;                              // becomes cur
        }
        __syncthreads();
        for (int i = t; i < rem; i += 256) {
            int d = ldst[i];
            int b = d / BSZ;
            int r = atomicAdd(&h[b], 1);
            pairs[b * BCAP + wbase[b] + r] =
                ((unsigned)(d - b * BSZ) << 17) | (unsigned)lsrc[i];
        }
        return;
    }
    blk -= NWG;
    if (blk < XBLKS) {
        int idx = blk * 256 + t;
        if (idx >= N_NODES * 12) return;
        const float4* x4 = (const float4*)x;
        float4 u = x4[(size_t)idx * 2];
        float4 v = x4[(size_t)idx * 2 + 1];
        uint4 w;
        w.x = pack2(u.x, u.y); w.y = pack2(u.z, u.w);
        w.z = pack2(v.x, v.y); w.w = pack2(v.z, v.w);
        xb4[idx] = w;
    } else {
        int i = (blk - XBLKS) * 256 + t;
        if (i < 128 * 192) {
            int col = i / 192, k = i - col * 192;
            float v = (k < 96) ? w1l[k * 128 + col] : w1r[(k - 96) * 128 + col];
            wt1[i] = (unsigned short)f2bf(v);
        } else {
            int j = i - 128 * 192;
            int col = j / 128, k = j - col * 128;
            float v = (col < 64) ? w2l[k * 64 + col] : w2r[k * 64 + col - 64];
            wt2[j] = (unsigned short)f2bf(v);
        }
    }
}

// ---------------------------------------------------------------------------
// CSR pass 2: per-bucket fine CSR (bucket b region = [b*BCAP, b*BCAP+gcnt[b])).
// LDS 250-bin histogram + scan + rank; uint4-vectorized 4-wide loops.
// ---------------------------------------------------------------------------
__global__ __launch_bounds__(256) void partb_csr(
    const unsigned int* __restrict__ pairs, const int* __restrict__ gcnt,
    int* __restrict__ rowstart, int* __restrict__ cnt,
    int* __restrict__ adj)
{
    __shared__ int h[256];
    __shared__ int buf[256];
    __shared__ int cur[256];
    int b = blockIdx.x;
    int t = threadIdx.x;
    int beg = b * BCAP;
    int n = gcnt[b];
    int node0 = b * BSZ;
    h[t] = 0;
    __syncthreads();
    const uint4* p4 = (const uint4*)(pairs + beg);
    int nv = n >> 2;
    for (int k = t; k < nv; k += 256) {
        uint4 u = p4[k];
        atomicAdd(&h[u.x >> 17], 1);
        atomicAdd(&h[u.y >> 17], 1);
        atomicAdd(&h[u.z >> 17], 1);
        atomicAdd(&h[u.w >> 17], 1);
    }
    for (int i = (nv << 2) + t; i < n; i += 256)
        atomicAdd(&h[pairs[beg + i] >> 17], 1);
    __syncthreads();
    int c = h[t];
    buf[t] = c;
    __syncthreads();
    for (int off = 1; off < 256; off <<= 1) {       // inclusive scan
        int v = (t >= off) ? buf[t - off] : 0;
        __syncthreads();
        buf[t] += v;
        __syncthreads();
    }
    int excl = buf[t] - c;
    if (t < BSZ) {
        rowstart[node0 + t] = beg + excl;
        cnt[node0 + t] = c;
    }
    cur[t] = beg + excl;
    __syncthreads();
    for (int k = t; k < nv; k += 256) {
        uint4 u = p4[k];
        int p0 = atomicAdd(&cur[u.x >> 17], 1);
        int p1 = atomicAdd(&cur[u.y >> 17], 1);
        int p2 = atomicAdd(&cur[u.z >> 17], 1);
        int p3 = atomicAdd(&cur[u.w >> 17], 1);
        adj[p0] = (int)(u.x & 0x1FFFFu);
        adj[p1] = (int)(u.y & 0x1FFFFu);
        adj[p2] = (int)(u.z & 0x1FFFFu);
        adj[p3] = (int)(u.w & 0x1FFFFu);
    }
    for (int i = (nv << 2) + t; i < n; i += 256) {
        unsigned int u = pairs[beg + i];
        int pos = atomicAdd(&cur[u >> 17], 1);
        adj[pos] = (int)(u & 0x1FFFFu);
    }
}

// ---------------------------------------------------------------------------
// Gather 1: agg[n] = (sum_{j in N(n)} xb[j]) / deg(n), bf16 out [50000][96].
// thread = (node, 16B chunk c in 0..11); 4-edge unroll. Max thread count --
// gathers are chip-level outstanding-request bound (R8 lesson).
// ---------------------------------------------------------------------------
__global__ __launch_bounds__(256) void gather1_kernel(
    const int* __restrict__ rowstart, const int* __restrict__ cnt,
    const int* __restrict__ adj, const uint4* __restrict__ xb4,
    uint4* __restrict__ agg4)
{
    int idx = blockIdx.x * 256 + threadIdx.x;
    if (idx >= N_NODES * 12) return;
    int node = idx / 12;
    int c = idx - node * 12;
    int beg = rowstart[node];
    int d = cnt[node];
    int end = beg + d;
    float a0=0,a1=0,a2=0,a3=0,a4=0,a5=0,a6=0,a7=0;
    float b0=0,b1=0,b2=0,b3=0,b4=0,b5=0,b6=0,b7=0;
    int j = beg;
    for (; j + 3 < end; j += 4) {
        int s0 = adj[j];
        int s1 = adj[j + 1];
        int s2 = adj[j + 2];
        int s3 = adj[j + 3];
        uint4 u = xb4[(size_t)s0 * 12 + c];
        uint4 v = xb4[(size_t)s1 * 12 + c];
        uint4 w = xb4[(size_t)s2 * 12 + c];
        uint4 z = xb4[(size_t)s3 * 12 + c];
        a0 += blo(u.x); a1 += bhi(u.x); a2 += blo(u.y); a3 += bhi(u.y);
        a4 += blo(u.z); a5 += bhi(u.z); a6 += blo(u.w); a7 += bhi(u.w);
        b0 += blo(v.x); b1 += bhi(v.x); b2 += blo(v.y); b3 += bhi(v.y);
        b4 += blo(v.z); b5 += bhi(v.z); b6 += blo(v.w); b7 += bhi(v.w);
        a0 += blo(w.x); a1 += bhi(w.x); a2 += blo(w.y); a3 += bhi(w.y);
        a4 += blo(w.z); a5 += bhi(w.z); a6 += blo(w.w); a7 += bhi(w.w);
        b0 += blo(z.x); b1 += bhi(z.x); b2 += blo(z.y); b3 += bhi(z.y);
        b4 += blo(z.z); b5 += bhi(z.z); b6 += blo(z.w); b7 += bhi(z.w);
    }
    for (; j < end; j++) {
        int s0 = adj[j];
        uint4 u = xb4[(size_t)s0 * 12 + c];
        a0 += blo(u.x); a1 += bhi(u.x); a2 += blo(u.y); a3 += bhi(u.y);
        a4 += blo(u.z); a5 += bhi(u.z); a6 += blo(u.w); a7 += bhi(u.w);
    }
    a0 += b0; a1 += b1; a2 += b2; a3 += b3;
    a4 += b4; a5 += b5; a6 += b6; a7 += b7;
    float id = 1.0f / (float)max(d, 1);
    uint4 w;
    w.x = pack2(a0 * id, a1 * id); w.y = pack2(a2 * id, a3 * id);
    w.z = pack2(a4 * id, a5 * id); w.w = pack2(a6 * id, a7 * id);
    agg4[(size_t)node * 12 + c] = w;
}

// ---------------------------------------------------------------------------
// Fused GEMM1+GEMM2 (bf16 MFMA), 64-row tiles. R7-proven: weights loaded
// global->registers per lane (L2-hot 81KB, statically-known fragments);
// LDS = A-tile only (25.6KB) -> ~4 blocks/CU.
//   h  = relu([agg|x] @ W1t^T + b1)  in LDS; [p|q] = h @ W2t^T.
// ---------------------------------------------------------------------------
__global__ __launch_bounds__(256) void gemm12_fused(
    const uint4* __restrict__ agg4, const uint4* __restrict__ xb4,
    const uint4* __restrict__ w1t4, const uint4* __restrict__ w2t4,
    const float* __restrict__ b1, const float* __restrict__ b2,
    unsigned short* __restrict__ p, float* __restrict__ out)
{
    constexpr int KP = 200;   // stage-1 A stride in shorts (192+8 pad)
    constexpr int KQ = 136;   // stage-2 A stride in shorts (128+8 pad)
    __shared__ unsigned short la[64 * KP];    // 25600 B (reused for h-tile)
    int t = threadIdx.x;
    uint4* la4 = (uint4*)la;

    int wave = t >> 6, lane = t & 63;
    int m = lane & 15, half = lane >> 4;          // half: 0..3
    int koff = half * 8;

    // B1 fragments from global (issued first; overlap A-staging latency).
    // W1t is [128][192] bf16 = [128][24] short8; frag = col*24 + kk*4 + half.
    const short8* w1s = (const short8*)w1t4;
    short8 B1r[6][2];
#pragma unroll
    for (int kk = 0; kk < 6; kk++) {
        B1r[kk][0] = w1s[(wave * 32 + m)      * 24 + kk * 4 + half];
        B1r[kk][1] = w1s[(wave * 32 + 16 + m) * 24 + kk * 4 + half];
    }

    // stage A [64][192]: k 0..95 from agg, 96..191 from xb
    int row0 = blockIdx.x * 64;
    for (int i = t; i < 64 * 24; i += 256) {
        int r = i / 24, c = i - r * 24;
        // rows >= N_NODES read pad rows (valid mem, rows discarded)
        la4[r * 25 + c] = (c < 12)
            ? agg4[(size_t)(row0 + r) * 12 + c]
            : xb4[(size_t)(row0 + r) * 12 + (c - 12)];
    }
    __syncthreads();

    f32x4 acc[4][2] = {};
#pragma unroll
    for (int kk = 0; kk < 6; kk++) {
        int k0 = kk * 32;
#pragma unroll
        for (int g = 0; g < 4; g++) {
            short8 A = *(const short8*)&la[(g * 16 + m) * KP + k0 + koff];
            acc[g][0] = __builtin_amdgcn_mfma_f32_16x16x32_bf16(A, B1r[kk][0], acc[g][0], 0, 0, 0);
            acc[g][1] = __builtin_amdgcn_mfma_f32_16x16x32_bf16(A, B1r[kk][1], acc[g][1], 0, 0, 0);
        }
    }
    __syncthreads();   // all waves done reading la before h overwrite

    // B2 fragments from global (issued before h-write to hide L2 latency).
    // W2t is [128][128] bf16 = [128][16] short8.
    const short8* w2s = (const short8*)w2t4;
    short8 B2r[4][2];
#pragma unroll
    for (int kk = 0; kk < 4; kk++) {
        B2r[kk][0] = w2s[(wave * 32 + m)      * 16 + kk * 4 + half];
        B2r[kk][1] = w2s[(wave * 32 + 16 + m) * 16 + kk * 4 + half];
    }

    // h-tile (bias+relu, bf16) -> la with stride KQ
    int col0 = wave * 32 + m, col1 = col0 + 16;
    {
        float bias0 = b1[col0], bias1 = b1[col1];
#pragma unroll
        for (int g = 0; g < 4; g++) {
#pragma unroll
            for (int reg = 0; reg < 4; reg++) {
                int hr = g * 16 + half * 4 + reg;
                la[hr * KQ + col0] = (unsigned short)f2bf(fmaxf(acc[g][0][reg] + bias0, 0.f));
                la[hr * KQ + col1] = (unsigned short)f2bf(fmaxf(acc[g][1][reg] + bias1, 0.f));
            }
        }
    }
    __syncthreads();

    f32x4 acc2[4][2] = {};
#pragma unroll
    for (int kk = 0; kk < 4; kk++) {
        int k0 = kk * 32;
#pragma unroll
        for (int g = 0; g < 4; g++) {
            short8 A = *(const short8*)&la[(g * 16 + m) * KQ + k0 + koff];
            acc2[g][0] = __builtin_amdgcn_mfma_f32_16x16x32_bf16(A, B2r[kk][0], acc2[g][0], 0, 0, 0);
            acc2[g][1] = __builtin_amdgcn_mfma_f32_16x16x32_bf16(A, B2r[kk][1], acc2[g][1], 0, 0, 0);
        }
    }
#pragma unroll
    for (int g = 0; g < 4; g++) {
#pragma unroll
        for (int reg = 0; reg < 4; reg++) {
            int r = row0 + g * 16 + half * 4 + reg;
            if (r >= N_NODES) continue;
            float v0 = acc2[g][0][reg], v1 = acc2[g][1][reg];
            if (col0 < 64) p[(size_t)r * 64 + col0] = (unsigned short)f2bf(v0);
            else           out[(size_t)r * 64 + col0 - 64] = v0 + b2[col0 - 64];
            if (col1 < 64) p[(size_t)r * 64 + col1] = (unsigned short)f2bf(v1);
            else           out[(size_t)r * 64 + col1 - 64] = v1 + b2[col1 - 64];
        }
    }
}

// ---------------------------------------------------------------------------
// Gather 2 + finalize: out[n] += (sum_{j in N(n)} p[j]) / deg(n)
// thread = (node, 16B chunk c in 0..7); 4-edge unroll (R4-proven).
// ---------------------------------------------------------------------------
__global__ __launch_bounds__(256) void gather2_kernel(
    const int* __restrict__ rowstart, const int* __restrict__ cnt,
    const int* __restrict__ adj, const uint4* __restrict__ p4,
    float* __restrict__ out)
{
    int idx = blockIdx.x * 256 + threadIdx.x;
    if (idx >= N_NODES * 8) return;
    int node = idx >> 3;
    int c = idx & 7;
    int beg = rowstart[node];
    int d = cnt[node];
    int end = beg + d;
    float a0=0,a1=0,a2=0,a3=0,a4=0,a5=0,a6=0,a7=0;
    float b0=0,b1=0,b2=0,b3=0,b4=0,b5=0,b6=0,b7=0;
    int j = beg;
    for (; j + 3 < end; j += 4) {
        int s0 = adj[j];
        int s1 = adj[j + 1];
        int s2 = adj[j + 2];
        int s3 = adj[j + 3];
        uint4 u = p4[(size_t)s0 * 8 + c];
        uint4 v = p4[(size_t)s1 * 8 + c];
        uint4 w = p4[(size_t)s2 * 8 + c];
        uint4 z = p4[(size_t)s3 * 8 + c];
        a0 += blo(u.x); a1 += bhi(u.x); a2 += blo(u.y); a3 += bhi(u.y);
        a4 += blo(u.z); a5 += bhi(u.z); a6 += blo(u.w); a7 += bhi(u.w);
        b0 += blo(v.x); b1 += bhi(v.x); b2 += blo(v.y); b3 += bhi(v.y);
        b4 += blo(v.z); b5 += bhi(v.z); b6 += blo(v.w); b7 += bhi(v.w);
        a0 += blo(w.x); a1 += bhi(w.x); a2 += blo(w.y); a3 += bhi(w.y);
        a4 += blo(w.z); a5 += bhi(w.z); a6 += blo(w.w); a7 += bhi(w.w);
        b0 += blo(z.x); b1 += bhi(z.x); b2 += blo(z.y); b3 += bhi(z.y);
        b4 += blo(z.z); b5 += bhi(z.z); b6 += blo(z.w); b7 += bhi(z.w);
    }
    for (; j < end; j++) {
        int s0 = adj[j];
        uint4 u = p4[(size_t)s0 * 8 + c];
        a0 += blo(u.x); a1 += bhi(u.x); a2 += blo(u.y); a3 += bhi(u.y);
        a4 += blo(u.z); a5 += bhi(u.z); a6 += blo(u.w); a7 += bhi(u.w);
    }
    a0 += b0; a1 += b1; a2 += b2; a3 += b3;
    a4 += b4; a5 += b5; a6 += b6; a7 += b7;
    float id = 1.0f / (float)max(d, 1);
    float4* o4 = (float4*)out;
    size_t base = (size_t)node * 16 + 2 * c;
    float4 u = o4[base], v = o4[base + 1];
    u.x = fmaf(a0, id, u.x); u.y = fmaf(a1, id, u.y);
    u.z = fmaf(a2, id, u.z); u.w = fmaf(a3, id, u.w);
    v.x = fmaf(a4, id, v.x); v.y = fmaf(a5, id, v.y);
    v.z = fmaf(a6, id, v.z); v.w = fmaf(a7, id, v.w);
    o4[base] = u; o4[base + 1] = v;
}

extern "C" void kernel_launch(void* const* d_in, const int* in_sizes, int n_in,
                              void* d_out, int out_size, void* d_ws, size_t ws_size,
                              hipStream_t stream)
{
    const float* x   = (const float*)d_in[0];
    const int*   ei  = (const int*)d_in[1];
    const float* w1l = (const float*)d_in[2];
    const float* w1r = (const float*)d_in[3];
    const float* b1  = (const float*)d_in[4];
    const float* w2l = (const float*)d_in[5];
    const float* w2r = (const float*)d_in[6];
    const float* b2  = (const float*)d_in[7];
    float* out = (float*)d_out;

    int E = in_sizes[1] / 2;                  // edge_index is [2, E]
    const int* src = ei;
    const int* dst = ei + E;

    // Workspace layout (4B units, arrays kept 16B-aligned).
    int* gcnt     = (int*)d_ws;                        // 256 (200 used)
    int* cnt      = gcnt + 256;                        // 50000
    int* rowstart = cnt + N_NODES;                     // 50000
    unsigned int* pairs = (unsigned int*)(rowstart + N_NODES); // NB*BCAP
    int* adj      = (int*)(pairs + NB * BCAP);         // NB*BCAP
    unsigned short* xb  = (unsigned short*)(adj + NB * BCAP); // MROWS*96 bf16
    unsigned short* agg = xb + (size_t)MROWS * IN_C;   // MROWS*96 bf16
    unsigned short* p   = agg + (size_t)MROWS * IN_C;  // 50000*64 bf16
    unsigned short* Wt1 = p  + (size_t)N_NODES * 64;   // 128*192 bf16
    unsigned short* Wt2 = Wt1 + 128 * 192;             // 128*128 bf16

    // zero bucket counters (stream-ordered, capture-safe)
    hipMemsetAsync(gcnt, 0, NB * sizeof(int), stream);

    // fused: bucket scatter (blocks 0..NWG, latency-bound) + conv streaming
    scatter_conv_kernel<<<NWG + XBLKS + WBLKS, 256, 0, stream>>>(
        src, dst, gcnt, pairs, E,
        x, (uint4*)xb, w1l, w1r, w2l, w2r, Wt1, Wt2);

    partb_csr<<<NB, 256, 0, stream>>>(pairs, gcnt, rowstart, cnt, adj);

    gather1_kernel<<<(N_NODES * 12 + 255) / 256, 256, 0, stream>>>(
        rowstart, cnt, adj, (const uint4*)xb, (uint4*)agg);

    gemm12_fused<<<MROWS / 64, 256, 0, stream>>>(
        (const uint4*)agg, (const uint4*)xb, (const uint4*)Wt1, (const uint4*)Wt2,
        b1, b2, p, out);

    gather2_kernel<<<(N_NODES * 8 + 255) / 256, 256, 0, stream>>>(
        rowstart, cnt, adj, (const uint4*)p, out);
}